// Round 2
// baseline (3431.968 us; speedup 1.0000x reference)
//
#include <hip/hip_runtime.h>
#include <hip/hip_cooperative_groups.h>

namespace cg = cooperative_groups;

// 3D reaction-diffusion tumor solver, 160^3 f32 grid, 30 explicit Euler steps.
// R4: gated persistent cooperative kernel + proven multi-launch fallback.
//
// R3 post-mortem: output was all zeros (absmax == max|ref|, no hang) -> the
// cooperative launch was REJECTED (1000 blocks needed exactly 4 blocks/CU
// co-residency; never verified, return code never checked). R4:
//   - coop grid shrunk to 500 blocks (needs only 2 blocks/CU; launch_bounds
//     (256,2) caps VGPR at 256 so the occupancy is compiler-guaranteed)
//   - runtime gates: coop-launch attr, occupancy query (maxBlocks*CU >= 500),
//     and the launch return code
//   - fallback: the R2 kernel that passed at 476 us, verbatim.
// Each coop thread owns 8 float4 groups (z-slabs of 20 planes), keeps ther
// and its own center values in registers across all 30 steps.

#define NX 160
#define NY 160
#define NZ 160
#define NXQ (NX / 4)              // 40 float4 groups per row
#define NPLANE (NX * NY)          // 25600 floats per z-plane
#define NGROUPS (NZ * NY * NXQ)   // 1,024,000 float4 groups

// --- cooperative config: 8 groups/thread, z-slabs of 20 planes ---
#define GPT 8
#define ZSLAB (NZ / GPT)              // 20
#define CT_NTHREADS (NGROUPS / GPT)   // 128,000
#define CT_NBLOCKS (CT_NTHREADS / 256) // 500

// --- fallback config (R2): 2 groups/thread ---
#define FB_NTHREADS (NGROUPS / 2)     // 512,000
#define FB_NBLOCKS (FB_NTHREADS / 256) // 2000

__device__ __forceinline__ float4 ld4(const float* p) {
    return *reinterpret_cast<const float4*>(p);
}

// One group's update: load 4 vector + 2 scalar neighbors from rd, combine
// with register-resident center cc and therapy tm, return clipped c_{t+1}.
__device__ __forceinline__ float4 update_group(
    const float* rd, int base, float4 cc, float4 tm,
    int offym, int offyp, int offxl, int offxr, int offzm, int offzp,
    bool mym, bool myp, bool mxl, bool mxr, bool mzm, bool mzp,
    float D, float rho, float delta_t)
{
    float4 ym = ld4(rd + base + offym);
    float4 yp = ld4(rd + base + offyp);
    float4 zm = ld4(rd + base + offzm);
    float4 zp = ld4(rd + base + offzp);
    float  xl = rd[base + offxl];
    float  xr = rd[base + offxr];

    const float4 z4 = make_float4(0.f, 0.f, 0.f, 0.f);
    if (mym) ym = z4;
    if (myp) yp = z4;
    if (mzm) zm = z4;
    if (mzp) zp = z4;
    if (mxl) xl = 0.f;
    if (mxr) xr = 0.f;

    float4 o;
    float lap, g;
    lap = xl   + cc.y + ym.x + yp.x + zm.x + zp.x - 6.f * cc.x;
    g   = D * lap + rho * cc.x * (1.f - cc.x) - 2.f * tm.x * cc.x;
    o.x = fminf(fmaxf(cc.x + g * delta_t, 0.f), 1.f);
    lap = cc.x + cc.z + ym.y + yp.y + zm.y + zp.y - 6.f * cc.y;
    g   = D * lap + rho * cc.y * (1.f - cc.y) - 2.f * tm.y * cc.y;
    o.y = fminf(fmaxf(cc.y + g * delta_t, 0.f), 1.f);
    lap = cc.y + cc.w + ym.z + yp.z + zm.z + zp.z - 6.f * cc.z;
    g   = D * lap + rho * cc.z * (1.f - cc.z) - 2.f * tm.z * cc.z;
    o.z = fminf(fmaxf(cc.z + g * delta_t, 0.f), 1.f);
    lap = cc.z + xr   + ym.w + yp.w + zm.w + zp.w - 6.f * cc.w;
    g   = D * lap + rho * cc.w * (1.f - cc.w) - 2.f * tm.w * cc.w;
    o.w = fminf(fmaxf(cc.w + g * delta_t, 0.f), 1.f);
    return o;
}

// ---------------- cooperative all-steps kernel ----------------
__global__ __launch_bounds__(256, 2) void therapy_all(
    const float* __restrict__ c_init,
    const float* __restrict__ ther,
    float* __restrict__ out,
    float* __restrict__ ws,
    const float* __restrict__ Dp,
    const float* __restrict__ rhop,
    const float* __restrict__ dtp,
    const int* __restrict__ stepsp)
{
    cg::grid_group grid = cg::this_grid();
    const int tid = blockIdx.x * blockDim.x + threadIdx.x;

    const int xq = tid % NXQ;
    const int t2 = tid / NXQ;
    const int y  = t2 % NY;
    const int zq = t2 / NY;            // 0..19 within each z-slab

    const int   steps   = *stepsp;
    const float D       = *Dp;
    const float rho     = *rhop;
    const float delta_t = *dtp / (float)steps;

    const int  offym = (y > 0)        ? -NX : 0;
    const int  offyp = (y < NY - 1)   ?  NX : 0;
    const int  offxl = (xq > 0)       ? -1  : 0;
    const int  offxr = (xq < NXQ - 1) ?  4  : 3;
    const bool mym = (y == 0), myp = (y == NY - 1);
    const bool mxl = (xq == 0), mxr = (xq == NXQ - 1);

    const int base0 = tid * 4;   // group k lives at base0 + k*ZSLAB*NPLANE

    // Persistent register state (fully unrolled -> static indices -> VGPRs).
    float4 tv[GPT], cv[GPT];
#pragma unroll
    for (int k = 0; k < GPT; ++k) {
        tv[k] = ld4(ther   + base0 + k * ZSLAB * NPLANE);
        cv[k] = ld4(c_init + base0 + k * ZSLAB * NPLANE);
    }

    const float* rd = c_init;
    for (int i = 0; i < steps; ++i) {
        // Ping-pong so the final step lands in `out` for any step count.
        float* wr = ((steps - 1 - i) & 1) ? ws : out;
#pragma unroll
        for (int k = 0; k < GPT; ++k) {
            const bool mzm = (k == 0)       && (zq == 0);         // z == 0
            const bool mzp = (k == GPT - 1) && (zq == ZSLAB - 1); // z == 159
            const int  base = base0 + k * ZSLAB * NPLANE;
            const float4 n = update_group(rd, base, cv[k], tv[k],
                offym, offyp, offxl, offxr,
                mzm ? 0 : -NPLANE, mzp ? 0 : NPLANE,
                mym, myp, mxl, mxr, mzm, mzp, D, rho, delta_t);
            *reinterpret_cast<float4*>(wr + base) = n;
            cv[k] = n;
        }
        rd = wr;
        if (i + 1 < steps) {
            __threadfence();   // device-scope visibility across XCDs
            grid.sync();
        }
    }
}

// ---------------- fallback per-step kernel (R2, passed @476us) ----------------
__global__ __launch_bounds__(256) void therapy_step(
    const float* __restrict__ src,
    const float* __restrict__ ther,
    float* __restrict__ dst,
    const float* __restrict__ Dp,
    const float* __restrict__ rhop,
    const float* __restrict__ dtp,
    const int* __restrict__ stepsp)
{
    const int tid = blockIdx.x * blockDim.x + threadIdx.x;

    const int xq = tid % NXQ;
    const int t2 = tid / NXQ;
    const int y  = t2 % NY;
    const int z0 = t2 / NY;             // 0..79
    const int base0 = tid * 4;          // group 0: z in [0,80)
    const int base1 = base0 + 80 * NPLANE;  // group 1: z in [80,160)

    const int offym = (y > 0)        ? -NX : 0;
    const int offyp = (y < NY - 1)   ?  NX : 0;
    const int offxl = (xq > 0)       ? -1  : 0;
    const int offxr = (xq < NXQ - 1) ?  4  : 3;
    const int offzm0 = (z0 > 0)      ? -NPLANE : 0;
    const int offzp1 = (z0 < 79)     ?  NPLANE : 0;

    const float4 cc0 = ld4(src + base0);
    const float4 cc1 = ld4(src + base1);
    float4 ym0 = ld4(src + base0 + offym);
    float4 ym1 = ld4(src + base1 + offym);
    float4 yp0 = ld4(src + base0 + offyp);
    float4 yp1 = ld4(src + base1 + offyp);
    float4 zm0 = ld4(src + base0 + offzm0);
    const float4 zm1 = ld4(src + base1 - NPLANE);
    const float4 zp0 = ld4(src + base0 + NPLANE);
    float4 zp1 = ld4(src + base1 + offzp1);
    float xl0 = src[base0 + offxl];
    float xl1 = src[base1 + offxl];
    float xr0 = src[base0 + offxr];
    float xr1 = src[base1 + offxr];
    const float4 tm0 = ld4(ther + base0);
    const float4 tm1 = ld4(ther + base1);

    const float D       = *Dp;
    const float rho     = *rhop;
    const float delta_t = *dtp / (float)(*stepsp);

    const float4 zero4 = make_float4(0.f, 0.f, 0.f, 0.f);
    if (y == 0)        { ym0 = zero4; ym1 = zero4; }
    if (y == NY - 1)   { yp0 = zero4; yp1 = zero4; }
    if (z0 == 0)       { zm0 = zero4; }
    if (z0 == 79)      { zp1 = zero4; }
    if (xq == 0)       { xl0 = 0.f; xl1 = 0.f; }
    if (xq == NXQ - 1) { xr0 = 0.f; xr1 = 0.f; }

    {
        const float lap0 = xl0   + cc0.y + ym0.x + yp0.x + zm0.x + zp0.x - 6.f * cc0.x;
        const float lap1 = cc0.x + cc0.z + ym0.y + yp0.y + zm0.y + zp0.y - 6.f * cc0.y;
        const float lap2 = cc0.y + cc0.w + ym0.z + yp0.z + zm0.z + zp0.z - 6.f * cc0.z;
        const float lap3 = cc0.z + xr0   + ym0.w + yp0.w + zm0.w + zp0.w - 6.f * cc0.w;
        float4 o;
        float g;
        g = D * lap0 + rho * cc0.x * (1.f - cc0.x) - 2.f * tm0.x * cc0.x;
        o.x = fminf(fmaxf(cc0.x + g * delta_t, 0.f), 1.f);
        g = D * lap1 + rho * cc0.y * (1.f - cc0.y) - 2.f * tm0.y * cc0.y;
        o.y = fminf(fmaxf(cc0.y + g * delta_t, 0.f), 1.f);
        g = D * lap2 + rho * cc0.z * (1.f - cc0.z) - 2.f * tm0.z * cc0.z;
        o.z = fminf(fmaxf(cc0.z + g * delta_t, 0.f), 1.f);
        g = D * lap3 + rho * cc0.w * (1.f - cc0.w) - 2.f * tm0.w * cc0.w;
        o.w = fminf(fmaxf(cc0.w + g * delta_t, 0.f), 1.f);
        *reinterpret_cast<float4*>(dst + base0) = o;
    }
    {
        const float lap0 = xl1   + cc1.y + ym1.x + yp1.x + zm1.x + zp1.x - 6.f * cc1.x;
        const float lap1 = cc1.x + cc1.z + ym1.y + yp1.y + zm1.y + zp1.y - 6.f * cc1.y;
        const float lap2 = cc1.y + cc1.w + ym1.z + yp1.z + zm1.z + zp1.z - 6.f * cc1.z;
        const float lap3 = cc1.z + xr1   + ym1.w + yp1.w + zm1.w + zp1.w - 6.f * cc1.w;
        float4 o;
        float g;
        g = D * lap0 + rho * cc1.x * (1.f - cc1.x) - 2.f * tm1.x * cc1.x;
        o.x = fminf(fmaxf(cc1.x + g * delta_t, 0.f), 1.f);
        g = D * lap1 + rho * cc1.y * (1.f - cc1.y) - 2.f * tm1.y * cc1.y;
        o.y = fminf(fmaxf(cc1.y + g * delta_t, 0.f), 1.f);
        g = D * lap2 + rho * cc1.z * (1.f - cc1.z) - 2.f * tm1.z * cc1.z;
        o.z = fminf(fmaxf(cc1.z + g * delta_t, 0.f), 1.f);
        g = D * lap3 + rho * cc1.w * (1.f - cc1.w) - 2.f * tm1.w * cc1.w;
        o.w = fminf(fmaxf(cc1.w + g * delta_t, 0.f), 1.f);
        *reinterpret_cast<float4*>(dst + base1) = o;
    }
}

extern "C" void kernel_launch(void* const* d_in, const int* in_sizes, int n_in,
                              void* d_out, int out_size, void* d_ws, size_t ws_size,
                              hipStream_t stream) {
    const float* c_init = (const float*)d_in[0];
    const float* Dp     = (const float*)d_in[1];
    const float* rhop   = (const float*)d_in[2];
    const float* dtp    = (const float*)d_in[3];
    const float* ther   = (const float*)d_in[4];
    const int*   stepsp = (const int*)d_in[5];

    float* out = (float*)d_out;
    float* wsA = (float*)d_ws;   // ping-pong buffer (16.4 MB)

    // ---- gate the cooperative path (computed once) ----
    static int coop_ok = -1;
    if (coop_ok < 0) {
        coop_ok = 0;
        int dev = 0;
        if (hipGetDevice(&dev) == hipSuccess) {
            int coopAttr = 0, ncu = 0, maxb = 0;
            if (hipDeviceGetAttribute(&coopAttr, hipDeviceAttributeCooperativeLaunch, dev) == hipSuccess &&
                coopAttr != 0 &&
                hipDeviceGetAttribute(&ncu, hipDeviceAttributeMultiprocessorCount, dev) == hipSuccess &&
                hipOccupancyMaxActiveBlocksPerMultiprocessor(
                    &maxb, (const void*)therapy_all, 256, 0) == hipSuccess &&
                (long)maxb * (long)ncu >= (long)CT_NBLOCKS) {
                coop_ok = 1;
            }
        }
    }

    if (coop_ok == 1) {
        void* args[] = {
            (void*)&c_init, (void*)&ther, (void*)&out, (void*)&wsA,
            (void*)&Dp, (void*)&rhop, (void*)&dtp, (void*)&stepsp
        };
        if (hipLaunchCooperativeKernel((void*)therapy_all,
                                       dim3(CT_NBLOCKS), dim3(256),
                                       args, 0, stream) == hipSuccess) {
            return;
        }
        coop_ok = 0;  // launch rejected -> permanent fallback
    }

    // ---- fallback: 30 per-step launches (proven R2 path) ----
    const dim3 block(256);
    const dim3 grid(FB_NBLOCKS);
    const float* src = c_init;
    for (int i = 0; i < 30; ++i) {
        float* dst = (i & 1) ? out : wsA;
        therapy_step<<<grid, block, 0, stream>>>(src, ther, dst, Dp, rhop, dtp, stepsp);
        src = dst;
    }
}

// Round 3
// 914.745 us; speedup vs baseline: 3.7518x; 3.7518x over previous
//
#include <hip/hip_runtime.h>
#include <hip/hip_cooperative_groups.h>

namespace cg = cooperative_groups;

// 3D reaction-diffusion tumor solver, 160^3 f32 grid, 30 explicit Euler steps.
// R5: persistent cooperative kernel with a HAND-ROLLED grid barrier.
//
// R4 post-mortem: cooperative path ran correctly (1 dispatch, co-resident)
// but stock cg::grid_group::sync() cost ~110 us/sync on 500 blocks x 8 XCDs
// (single-counter device-scope atomic barrier + acquire-fenced polling) ->
// 3.48 ms total. R5 replaces it with a distributed flag barrier:
//   arrive : each block release-stores an epoch to its OWN 64B-strided flag
//            (parallel stores, no RMW contention)
//   scan   : block 0's 256 threads poll all 500 flags with RELAXED agent
//            loads (no cache-invalidate per poll), one acquire fence, then
//            release-store a single `go` flag
//   release: other blocks relaxed-poll `go`, one acquire fence, syncthreads
// Epochs increase monotonically across launches/graph-replays via
// g_epoch_base, so flags never need resetting.
//
// Compute phase unchanged from R4 (correct): 500 blocks x 256 threads,
// 8 float4 groups/thread (z-slabs of 20 planes), ther + own center values
// register-resident across all steps.

#define NX 160
#define NY 160
#define NZ 160
#define NXQ (NX / 4)              // 40 float4 groups per row
#define NPLANE (NX * NY)          // 25600 floats per z-plane
#define NGROUPS (NZ * NY * NXQ)   // 1,024,000 float4 groups

// --- cooperative config: 8 groups/thread, z-slabs of 20 planes ---
#define GPT 8
#define ZSLAB (NZ / GPT)               // 20
#define CT_NTHREADS (NGROUPS / GPT)    // 128,000
#define CT_NBLOCKS (CT_NTHREADS / 256) // 500

// --- fallback config (R2): 2 groups/thread ---
#define FB_NTHREADS (NGROUPS / 2)      // 512,000
#define FB_NBLOCKS (FB_NTHREADS / 256) // 2000

// ---- barrier state (zero-init at module load; epochs monotonic forever) ----
__device__ unsigned int g_arrive[CT_NBLOCKS * 16];  // one flag per 64B line
__device__ unsigned int g_go;
__device__ unsigned int g_epoch_base;

__device__ __forceinline__ void grid_barrier(unsigned int e) {
    __syncthreads();  // all block threads done with this step's stores
    const int bid = blockIdx.x;
    const int tid = threadIdx.x;
    if (bid == 0) {
        if (tid == 0) {
            // release: flush this XCD's dirty L2 lines to coherence point
            __hip_atomic_store(&g_arrive[0], e, __ATOMIC_RELEASE,
                               __HIP_MEMORY_SCOPE_AGENT);
        }
        // parallel scan of all arrive flags, relaxed (cheap) polling
        for (int j = tid; j < CT_NBLOCKS; j += 256) {
            while (__hip_atomic_load(&g_arrive[j * 16], __ATOMIC_RELAXED,
                                     __HIP_MEMORY_SCOPE_AGENT) < e) {}
        }
        __syncthreads();
        if (tid == 0) {
            __builtin_amdgcn_fence(__ATOMIC_ACQUIRE, "agent");
            __hip_atomic_store(&g_go, e, __ATOMIC_RELEASE,
                               __HIP_MEMORY_SCOPE_AGENT);
        }
        __syncthreads();
    } else {
        if (tid == 0) {
            __hip_atomic_store(&g_arrive[bid * 16], e, __ATOMIC_RELEASE,
                               __HIP_MEMORY_SCOPE_AGENT);
            while (__hip_atomic_load(&g_go, __ATOMIC_RELAXED,
                                     __HIP_MEMORY_SCOPE_AGENT) < e) {
                __builtin_amdgcn_s_sleep(1);
            }
            __builtin_amdgcn_fence(__ATOMIC_ACQUIRE, "agent");
        }
        __syncthreads();
    }
}

__device__ __forceinline__ float4 ld4(const float* p) {
    return *reinterpret_cast<const float4*>(p);
}

// One group's update: load 4 vector + 2 scalar neighbors from rd, combine
// with register-resident center cc and therapy tm, return clipped c_{t+1}.
__device__ __forceinline__ float4 update_group(
    const float* rd, int base, float4 cc, float4 tm,
    int offym, int offyp, int offxl, int offxr, int offzm, int offzp,
    bool mym, bool myp, bool mxl, bool mxr, bool mzm, bool mzp,
    float D, float rho, float delta_t)
{
    float4 ym = ld4(rd + base + offym);
    float4 yp = ld4(rd + base + offyp);
    float4 zm = ld4(rd + base + offzm);
    float4 zp = ld4(rd + base + offzp);
    float  xl = rd[base + offxl];
    float  xr = rd[base + offxr];

    const float4 z4 = make_float4(0.f, 0.f, 0.f, 0.f);
    if (mym) ym = z4;
    if (myp) yp = z4;
    if (mzm) zm = z4;
    if (mzp) zp = z4;
    if (mxl) xl = 0.f;
    if (mxr) xr = 0.f;

    float4 o;
    float lap, g;
    lap = xl   + cc.y + ym.x + yp.x + zm.x + zp.x - 6.f * cc.x;
    g   = D * lap + rho * cc.x * (1.f - cc.x) - 2.f * tm.x * cc.x;
    o.x = fminf(fmaxf(cc.x + g * delta_t, 0.f), 1.f);
    lap = cc.x + cc.z + ym.y + yp.y + zm.y + zp.y - 6.f * cc.y;
    g   = D * lap + rho * cc.y * (1.f - cc.y) - 2.f * tm.y * cc.y;
    o.y = fminf(fmaxf(cc.y + g * delta_t, 0.f), 1.f);
    lap = cc.y + cc.w + ym.z + yp.z + zm.z + zp.z - 6.f * cc.z;
    g   = D * lap + rho * cc.z * (1.f - cc.z) - 2.f * tm.z * cc.z;
    o.z = fminf(fmaxf(cc.z + g * delta_t, 0.f), 1.f);
    lap = cc.z + xr   + ym.w + yp.w + zm.w + zp.w - 6.f * cc.w;
    g   = D * lap + rho * cc.w * (1.f - cc.w) - 2.f * tm.w * cc.w;
    o.w = fminf(fmaxf(cc.w + g * delta_t, 0.f), 1.f);
    return o;
}

// ---------------- cooperative all-steps kernel ----------------
__global__ __launch_bounds__(256, 2) void therapy_all(
    const float* __restrict__ c_init,
    const float* __restrict__ ther,
    float* __restrict__ out,
    float* __restrict__ ws,
    const float* __restrict__ Dp,
    const float* __restrict__ rhop,
    const float* __restrict__ dtp,
    const int* __restrict__ stepsp)
{
    const int tid = blockIdx.x * blockDim.x + threadIdx.x;

    const int xq = tid % NXQ;
    const int t2 = tid / NXQ;
    const int y  = t2 % NY;
    const int zq = t2 / NY;            // 0..19 within each z-slab

    const int   steps   = *stepsp;
    const float D       = *Dp;
    const float rho     = *rhop;
    const float delta_t = *dtp / (float)steps;

    // epoch base from previous launch (coherent at kernel-dispatch boundary)
    const unsigned int ebase = g_epoch_base;

    const int  offym = (y > 0)        ? -NX : 0;
    const int  offyp = (y < NY - 1)   ?  NX : 0;
    const int  offxl = (xq > 0)       ? -1  : 0;
    const int  offxr = (xq < NXQ - 1) ?  4  : 3;
    const bool mym = (y == 0), myp = (y == NY - 1);
    const bool mxl = (xq == 0), mxr = (xq == NXQ - 1);

    const int base0 = tid * 4;   // group k lives at base0 + k*ZSLAB*NPLANE

    // Persistent register state (fully unrolled -> static indices -> VGPRs).
    float4 tv[GPT], cv[GPT];
#pragma unroll
    for (int k = 0; k < GPT; ++k) {
        tv[k] = ld4(ther   + base0 + k * ZSLAB * NPLANE);
        cv[k] = ld4(c_init + base0 + k * ZSLAB * NPLANE);
    }

    const float* rd = c_init;
    for (int i = 0; i < steps; ++i) {
        // Ping-pong so the final step lands in `out` for any step count.
        float* wr = ((steps - 1 - i) & 1) ? ws : out;
#pragma unroll
        for (int k = 0; k < GPT; ++k) {
            const bool mzm = (k == 0)       && (zq == 0);         // z == 0
            const bool mzp = (k == GPT - 1) && (zq == ZSLAB - 1); // z == 159
            const int  base = base0 + k * ZSLAB * NPLANE;
            const float4 n = update_group(rd, base, cv[k], tv[k],
                offym, offyp, offxl, offxr,
                mzm ? 0 : -NPLANE, mzp ? 0 : NPLANE,
                mym, myp, mxl, mxr, mzm, mzp, D, rho, delta_t);
            *reinterpret_cast<float4*>(wr + base) = n;
            cv[k] = n;
        }
        rd = wr;
        if (i + 1 < steps) grid_barrier(ebase + (unsigned)i + 1u);
    }

    // Bump epoch base for the next launch/replay (epochs used: ebase+1 ..
    // ebase+steps-1). Safe: all blocks read ebase before barrier 1 completed,
    // and the next launch cannot start until this kernel fully retires.
    if (blockIdx.x == 0 && threadIdx.x == 0 && steps > 1) {
        g_epoch_base = ebase + (unsigned)steps - 1u;
    }
}

// ---------------- fallback per-step kernel (R2, passed @476us) ----------------
__global__ __launch_bounds__(256) void therapy_step(
    const float* __restrict__ src,
    const float* __restrict__ ther,
    float* __restrict__ dst,
    const float* __restrict__ Dp,
    const float* __restrict__ rhop,
    const float* __restrict__ dtp,
    const int* __restrict__ stepsp)
{
    const int tid = blockIdx.x * blockDim.x + threadIdx.x;

    const int xq = tid % NXQ;
    const int t2 = tid / NXQ;
    const int y  = t2 % NY;
    const int z0 = t2 / NY;             // 0..79
    const int base0 = tid * 4;          // group 0: z in [0,80)
    const int base1 = base0 + 80 * NPLANE;  // group 1: z in [80,160)

    const int offym = (y > 0)        ? -NX : 0;
    const int offyp = (y < NY - 1)   ?  NX : 0;
    const int offxl = (xq > 0)       ? -1  : 0;
    const int offxr = (xq < NXQ - 1) ?  4  : 3;
    const int offzm0 = (z0 > 0)      ? -NPLANE : 0;
    const int offzp1 = (z0 < 79)     ?  NPLANE : 0;

    const float4 cc0 = ld4(src + base0);
    const float4 cc1 = ld4(src + base1);
    float4 ym0 = ld4(src + base0 + offym);
    float4 ym1 = ld4(src + base1 + offym);
    float4 yp0 = ld4(src + base0 + offyp);
    float4 yp1 = ld4(src + base1 + offyp);
    float4 zm0 = ld4(src + base0 + offzm0);
    const float4 zm1 = ld4(src + base1 - NPLANE);
    const float4 zp0 = ld4(src + base0 + NPLANE);
    float4 zp1 = ld4(src + base1 + offzp1);
    float xl0 = src[base0 + offxl];
    float xl1 = src[base1 + offxl];
    float xr0 = src[base0 + offxr];
    float xr1 = src[base1 + offxr];
    const float4 tm0 = ld4(ther + base0);
    const float4 tm1 = ld4(ther + base1);

    const float D       = *Dp;
    const float rho     = *rhop;
    const float delta_t = *dtp / (float)(*stepsp);

    const float4 zero4 = make_float4(0.f, 0.f, 0.f, 0.f);
    if (y == 0)        { ym0 = zero4; ym1 = zero4; }
    if (y == NY - 1)   { yp0 = zero4; yp1 = zero4; }
    if (z0 == 0)       { zm0 = zero4; }
    if (z0 == 79)      { zp1 = zero4; }
    if (xq == 0)       { xl0 = 0.f; xl1 = 0.f; }
    if (xq == NXQ - 1) { xr0 = 0.f; xr1 = 0.f; }

    {
        const float lap0 = xl0   + cc0.y + ym0.x + yp0.x + zm0.x + zp0.x - 6.f * cc0.x;
        const float lap1 = cc0.x + cc0.z + ym0.y + yp0.y + zm0.y + zp0.y - 6.f * cc0.y;
        const float lap2 = cc0.y + cc0.w + ym0.z + yp0.z + zm0.z + zp0.z - 6.f * cc0.z;
        const float lap3 = cc0.z + xr0   + ym0.w + yp0.w + zm0.w + zp0.w - 6.f * cc0.w;
        float4 o;
        float g;
        g = D * lap0 + rho * cc0.x * (1.f - cc0.x) - 2.f * tm0.x * cc0.x;
        o.x = fminf(fmaxf(cc0.x + g * delta_t, 0.f), 1.f);
        g = D * lap1 + rho * cc0.y * (1.f - cc0.y) - 2.f * tm0.y * cc0.y;
        o.y = fminf(fmaxf(cc0.y + g * delta_t, 0.f), 1.f);
        g = D * lap2 + rho * cc0.z * (1.f - cc0.z) - 2.f * tm0.z * cc0.z;
        o.z = fminf(fmaxf(cc0.z + g * delta_t, 0.f), 1.f);
        g = D * lap3 + rho * cc0.w * (1.f - cc0.w) - 2.f * tm0.w * cc0.w;
        o.w = fminf(fmaxf(cc0.w + g * delta_t, 0.f), 1.f);
        *reinterpret_cast<float4*>(dst + base0) = o;
    }
    {
        const float lap0 = xl1   + cc1.y + ym1.x + yp1.x + zm1.x + zp1.x - 6.f * cc1.x;
        const float lap1 = cc1.x + cc1.z + ym1.y + yp1.y + zm1.y + zp1.y - 6.f * cc1.y;
        const float lap2 = cc1.y + cc1.w + ym1.z + yp1.z + zm1.z + zp1.z - 6.f * cc1.z;
        const float lap3 = cc1.z + xr1   + ym1.w + yp1.w + zm1.w + zp1.w - 6.f * cc1.w;
        float4 o;
        float g;
        g = D * lap0 + rho * cc1.x * (1.f - cc1.x) - 2.f * tm1.x * cc1.x;
        o.x = fminf(fmaxf(cc1.x + g * delta_t, 0.f), 1.f);
        g = D * lap1 + rho * cc1.y * (1.f - cc1.y) - 2.f * tm1.y * cc1.y;
        o.y = fminf(fmaxf(cc1.y + g * delta_t, 0.f), 1.f);
        g = D * lap2 + rho * cc1.z * (1.f - cc1.z) - 2.f * tm1.z * cc1.z;
        o.z = fminf(fmaxf(cc1.z + g * delta_t, 0.f), 1.f);
        g = D * lap3 + rho * cc1.w * (1.f - cc1.w) - 2.f * tm1.w * cc1.w;
        o.w = fminf(fmaxf(cc1.w + g * delta_t, 0.f), 1.f);
        *reinterpret_cast<float4*>(dst + base1) = o;
    }
}

extern "C" void kernel_launch(void* const* d_in, const int* in_sizes, int n_in,
                              void* d_out, int out_size, void* d_ws, size_t ws_size,
                              hipStream_t stream) {
    const float* c_init = (const float*)d_in[0];
    const float* Dp     = (const float*)d_in[1];
    const float* rhop   = (const float*)d_in[2];
    const float* dtp    = (const float*)d_in[3];
    const float* ther   = (const float*)d_in[4];
    const int*   stepsp = (const int*)d_in[5];

    float* out = (float*)d_out;
    float* wsA = (float*)d_ws;   // ping-pong buffer (16.4 MB)

    // ---- gate the cooperative path (computed once) ----
    static int coop_ok = -1;
    if (coop_ok < 0) {
        coop_ok = 0;
        int dev = 0;
        if (hipGetDevice(&dev) == hipSuccess) {
            int coopAttr = 0, ncu = 0, maxb = 0;
            if (hipDeviceGetAttribute(&coopAttr, hipDeviceAttributeCooperativeLaunch, dev) == hipSuccess &&
                coopAttr != 0 &&
                hipDeviceGetAttribute(&ncu, hipDeviceAttributeMultiprocessorCount, dev) == hipSuccess &&
                hipOccupancyMaxActiveBlocksPerMultiprocessor(
                    &maxb, (const void*)therapy_all, 256, 0) == hipSuccess &&
                (long)maxb * (long)ncu >= (long)CT_NBLOCKS) {
                coop_ok = 1;
            }
        }
    }

    if (coop_ok == 1) {
        void* args[] = {
            (void*)&c_init, (void*)&ther, (void*)&out, (void*)&wsA,
            (void*)&Dp, (void*)&rhop, (void*)&dtp, (void*)&stepsp
        };
        if (hipLaunchCooperativeKernel((void*)therapy_all,
                                       dim3(CT_NBLOCKS), dim3(256),
                                       args, 0, stream) == hipSuccess) {
            return;
        }
        coop_ok = 0;  // launch rejected -> permanent fallback
    }

    // ---- fallback: 30 per-step launches (proven R2 path) ----
    const dim3 block(256);
    const dim3 grid(FB_NBLOCKS);
    const float* src = c_init;
    for (int i = 0; i < 30; ++i) {
        float* dst = (i & 1) ? out : wsA;
        therapy_step<<<grid, block, 0, stream>>>(src, ther, dst, Dp, rhop, dtp, stepsp);
        src = dst;
    }
}

// Round 4
// 471.069 us; speedup vs baseline: 7.2855x; 1.9418x over previous
//
#include <hip/hip_runtime.h>
#include <hip/hip_cooperative_groups.h>

namespace cg = cooperative_groups;

// 3D reaction-diffusion tumor solver, 160^3 f32 grid, 30 explicit Euler steps.
// R6: persistent cooperative kernel, occupancy + register-residency fix.
//
// R5 post-mortem (831 us kernel): hand-rolled barrier worked, but
//   - occupancy 23.8% (2000 waves) -> 1.5 TB/s effective vs ~5 TB/s that the
//     2000-block multi-launch path sustained (acquire fence invalidates L2
//     every step, so all reads have L3 latency; needs waves to hide),
//   - VGPR_Count=64 while 8-group persistent state alone needs 64 -> compiler
//     rematerialized cv/tv from memory (FETCH 24.4 MB/step, not ~17).
// R6: 500 blocks x 512 threads, GPT=4 (state = 32 VGPRs, launch_bounds(512,4)
// caps 128), bijective XCD swizzle (m204) so each XCD owns contiguous z-y
// slabs (halo reads hit local L2 within a step), and per-XCD distributed
// `go` flags in the barrier release.

#define NX 160
#define NY 160
#define NZ 160
#define NXQ (NX / 4)              // 40 float4 groups per row
#define NPLANE (NX * NY)          // 25600 floats per z-plane
#define NGROUPS (NZ * NY * NXQ)   // 1,024,000 float4 groups

// --- cooperative config: 512-thread blocks, 4 groups/thread, z-quarters ---
#define GPT 4
#define ZSLAB (NZ / GPT)               // 40
#define CT_BS 512
#define CT_NTHREADS (NGROUPS / GPT)    // 256,000
#define CT_NBLOCKS (CT_NTHREADS / CT_BS) // 500

// --- fallback config (R2): 2 groups/thread ---
#define FB_NTHREADS (NGROUPS / 2)      // 512,000
#define FB_NBLOCKS (FB_NTHREADS / 256) // 2000

// ---- barrier state (zero-init at module load; epochs monotonic forever) ----
__device__ unsigned int g_arrive[CT_NBLOCKS * 16];  // one flag per 64B line
__device__ unsigned int g_go[8 * 16];               // per-XCD go lines
__device__ unsigned int g_epoch_base;

__device__ __forceinline__ void grid_barrier(unsigned int e) {
    __syncthreads();  // all block threads' stores issued & L2-acked (vmcnt 0)
    const int bid = blockIdx.x;
    const int tid = threadIdx.x;
    if (bid == 0) {
        if (tid == 0) {
            __hip_atomic_store(&g_arrive[0], e, __ATOMIC_RELEASE,
                               __HIP_MEMORY_SCOPE_AGENT);
        }
        // parallel scan of all arrive flags, relaxed (cheap) polling
        for (int j = tid; j < CT_NBLOCKS; j += CT_BS) {
            while (__hip_atomic_load(&g_arrive[j * 16], __ATOMIC_RELAXED,
                                     __HIP_MEMORY_SCOPE_AGENT) < e) {}
        }
        __syncthreads();
        if (tid == 0) {
            __builtin_amdgcn_fence(__ATOMIC_ACQUIRE, "agent");
#pragma unroll
            for (int x = 0; x < 8; ++x) {
                __hip_atomic_store(&g_go[x * 16], e, __ATOMIC_RELEASE,
                                   __HIP_MEMORY_SCOPE_AGENT);
            }
        }
        __syncthreads();
    } else {
        if (tid == 0) {
            __hip_atomic_store(&g_arrive[bid * 16], e, __ATOMIC_RELEASE,
                               __HIP_MEMORY_SCOPE_AGENT);
            while (__hip_atomic_load(&g_go[(bid & 7) * 16], __ATOMIC_RELAXED,
                                     __HIP_MEMORY_SCOPE_AGENT) < e) {
                __builtin_amdgcn_s_sleep(1);
            }
            __builtin_amdgcn_fence(__ATOMIC_ACQUIRE, "agent");
        }
        __syncthreads();
    }
}

__device__ __forceinline__ float4 ld4(const float* p) {
    return *reinterpret_cast<const float4*>(p);
}

// One group's update: load 4 vector + 2 scalar neighbors from rd, combine
// with register-resident center cc and therapy tm, return clipped c_{t+1}.
__device__ __forceinline__ float4 update_group(
    const float* rd, int base, float4 cc, float4 tm,
    int offym, int offyp, int offxl, int offxr, int offzm, int offzp,
    bool mym, bool myp, bool mxl, bool mxr, bool mzm, bool mzp,
    float D, float rho, float delta_t)
{
    float4 ym = ld4(rd + base + offym);
    float4 yp = ld4(rd + base + offyp);
    float4 zm = ld4(rd + base + offzm);
    float4 zp = ld4(rd + base + offzp);
    float  xl = rd[base + offxl];
    float  xr = rd[base + offxr];

    const float4 z4 = make_float4(0.f, 0.f, 0.f, 0.f);
    if (mym) ym = z4;
    if (myp) yp = z4;
    if (mzm) zm = z4;
    if (mzp) zp = z4;
    if (mxl) xl = 0.f;
    if (mxr) xr = 0.f;

    float4 o;
    float lap, g;
    lap = xl   + cc.y + ym.x + yp.x + zm.x + zp.x - 6.f * cc.x;
    g   = D * lap + rho * cc.x * (1.f - cc.x) - 2.f * tm.x * cc.x;
    o.x = fminf(fmaxf(cc.x + g * delta_t, 0.f), 1.f);
    lap = cc.x + cc.z + ym.y + yp.y + zm.y + zp.y - 6.f * cc.y;
    g   = D * lap + rho * cc.y * (1.f - cc.y) - 2.f * tm.y * cc.y;
    o.y = fminf(fmaxf(cc.y + g * delta_t, 0.f), 1.f);
    lap = cc.y + cc.w + ym.z + yp.z + zm.z + zp.z - 6.f * cc.z;
    g   = D * lap + rho * cc.z * (1.f - cc.z) - 2.f * tm.z * cc.z;
    o.z = fminf(fmaxf(cc.z + g * delta_t, 0.f), 1.f);
    lap = cc.z + xr   + ym.w + yp.w + zm.w + zp.w - 6.f * cc.w;
    g   = D * lap + rho * cc.w * (1.f - cc.w) - 2.f * tm.w * cc.w;
    o.w = fminf(fmaxf(cc.w + g * delta_t, 0.f), 1.f);
    return o;
}

// ---------------- cooperative all-steps kernel ----------------
__global__ __launch_bounds__(CT_BS, 4) void therapy_all(
    const float* __restrict__ c_init,
    const float* __restrict__ ther,
    float* __restrict__ out,
    float* __restrict__ ws,
    const float* __restrict__ Dp,
    const float* __restrict__ rhop,
    const float* __restrict__ dtp,
    const int* __restrict__ stepsp)
{
    // Bijective XCD swizzle (m204): blockIdx round-robins XCDs (xcd = bid%8),
    // remap so each XCD gets a CONTIGUOUS logical-block (= contiguous z-y
    // slab) range -> neighbor/halo reads hit the local XCD L2 within a step.
    const int q = CT_NBLOCKS / 8, r = CT_NBLOCKS % 8;   // 62, 4
    const int xcd  = blockIdx.x & 7;
    const int slot = blockIdx.x >> 3;
    const int lb   = (xcd < r) ? xcd * (q + 1) + slot
                               : r * (q + 1) + (xcd - r) * q + slot;
    const int tid = lb * CT_BS + threadIdx.x;

    const int xq = tid % NXQ;
    const int t2 = tid / NXQ;
    const int y  = t2 % NY;
    const int zq = t2 / NY;            // 0..39 within each z-quarter

    const int   steps   = *stepsp;
    const float D       = *Dp;
    const float rho     = *rhop;
    const float delta_t = *dtp / (float)steps;

    // epoch base from previous launch (coherent at kernel-dispatch boundary)
    const unsigned int ebase = g_epoch_base;

    const int  offym = (y > 0)        ? -NX : 0;
    const int  offyp = (y < NY - 1)   ?  NX : 0;
    const int  offxl = (xq > 0)       ? -1  : 0;
    const int  offxr = (xq < NXQ - 1) ?  4  : 3;
    const bool mym = (y == 0), myp = (y == NY - 1);
    const bool mxl = (xq == 0), mxr = (xq == NXQ - 1);

    const int base0 = tid * 4;   // group k lives at base0 + k*ZSLAB*NPLANE

    // Persistent register state (fully unrolled -> static indices -> VGPRs).
    float4 tv[GPT], cv[GPT];
#pragma unroll
    for (int k = 0; k < GPT; ++k) {
        tv[k] = ld4(ther   + base0 + k * ZSLAB * NPLANE);
        cv[k] = ld4(c_init + base0 + k * ZSLAB * NPLANE);
    }

    const float* rd = c_init;
    for (int i = 0; i < steps; ++i) {
        // Ping-pong so the final step lands in `out` for any step count.
        float* wr = ((steps - 1 - i) & 1) ? ws : out;
#pragma unroll
        for (int k = 0; k < GPT; ++k) {
            const bool mzm = (k == 0)       && (zq == 0);         // z == 0
            const bool mzp = (k == GPT - 1) && (zq == ZSLAB - 1); // z == 159
            const int  base = base0 + k * ZSLAB * NPLANE;
            const float4 n = update_group(rd, base, cv[k], tv[k],
                offym, offyp, offxl, offxr,
                mzm ? 0 : -NPLANE, mzp ? 0 : NPLANE,
                mym, myp, mxl, mxr, mzm, mzp, D, rho, delta_t);
            *reinterpret_cast<float4*>(wr + base) = n;
            cv[k] = n;
        }
        rd = wr;
        if (i + 1 < steps) grid_barrier(ebase + (unsigned)i + 1u);
    }

    // Bump epoch base for the next launch/replay (epochs used: ebase+1 ..
    // ebase+steps-1). Next launch cannot start until this kernel retires.
    if (blockIdx.x == 0 && threadIdx.x == 0 && steps > 1) {
        g_epoch_base = ebase + (unsigned)steps - 1u;
    }
}

// ---------------- fallback per-step kernel (R2, passed @476us) ----------------
__global__ __launch_bounds__(256) void therapy_step(
    const float* __restrict__ src,
    const float* __restrict__ ther,
    float* __restrict__ dst,
    const float* __restrict__ Dp,
    const float* __restrict__ rhop,
    const float* __restrict__ dtp,
    const int* __restrict__ stepsp)
{
    const int tid = blockIdx.x * blockDim.x + threadIdx.x;

    const int xq = tid % NXQ;
    const int t2 = tid / NXQ;
    const int y  = t2 % NY;
    const int z0 = t2 / NY;             // 0..79
    const int base0 = tid * 4;          // group 0: z in [0,80)
    const int base1 = base0 + 80 * NPLANE;  // group 1: z in [80,160)

    const int offym = (y > 0)        ? -NX : 0;
    const int offyp = (y < NY - 1)   ?  NX : 0;
    const int offxl = (xq > 0)       ? -1  : 0;
    const int offxr = (xq < NXQ - 1) ?  4  : 3;
    const int offzm0 = (z0 > 0)      ? -NPLANE : 0;
    const int offzp1 = (z0 < 79)     ?  NPLANE : 0;

    const float4 cc0 = ld4(src + base0);
    const float4 cc1 = ld4(src + base1);
    float4 ym0 = ld4(src + base0 + offym);
    float4 ym1 = ld4(src + base1 + offym);
    float4 yp0 = ld4(src + base0 + offyp);
    float4 yp1 = ld4(src + base1 + offyp);
    float4 zm0 = ld4(src + base0 + offzm0);
    const float4 zm1 = ld4(src + base1 - NPLANE);
    const float4 zp0 = ld4(src + base0 + NPLANE);
    float4 zp1 = ld4(src + base1 + offzp1);
    float xl0 = src[base0 + offxl];
    float xl1 = src[base1 + offxl];
    float xr0 = src[base0 + offxr];
    float xr1 = src[base1 + offxr];
    const float4 tm0 = ld4(ther + base0);
    const float4 tm1 = ld4(ther + base1);

    const float D       = *Dp;
    const float rho     = *rhop;
    const float delta_t = *dtp / (float)(*stepsp);

    const float4 zero4 = make_float4(0.f, 0.f, 0.f, 0.f);
    if (y == 0)        { ym0 = zero4; ym1 = zero4; }
    if (y == NY - 1)   { yp0 = zero4; yp1 = zero4; }
    if (z0 == 0)       { zm0 = zero4; }
    if (z0 == 79)      { zp1 = zero4; }
    if (xq == 0)       { xl0 = 0.f; xl1 = 0.f; }
    if (xq == NXQ - 1) { xr0 = 0.f; xr1 = 0.f; }

    {
        const float lap0 = xl0   + cc0.y + ym0.x + yp0.x + zm0.x + zp0.x - 6.f * cc0.x;
        const float lap1 = cc0.x + cc0.z + ym0.y + yp0.y + zm0.y + zp0.y - 6.f * cc0.y;
        const float lap2 = cc0.y + cc0.w + ym0.z + yp0.z + zm0.z + zp0.z - 6.f * cc0.z;
        const float lap3 = cc0.z + xr0   + ym0.w + yp0.w + zm0.w + zp0.w - 6.f * cc0.w;
        float4 o;
        float g;
        g = D * lap0 + rho * cc0.x * (1.f - cc0.x) - 2.f * tm0.x * cc0.x;
        o.x = fminf(fmaxf(cc0.x + g * delta_t, 0.f), 1.f);
        g = D * lap1 + rho * cc0.y * (1.f - cc0.y) - 2.f * tm0.y * cc0.y;
        o.y = fminf(fmaxf(cc0.y + g * delta_t, 0.f), 1.f);
        g = D * lap2 + rho * cc0.z * (1.f - cc0.z) - 2.f * tm0.z * cc0.z;
        o.z = fminf(fmaxf(cc0.z + g * delta_t, 0.f), 1.f);
        g = D * lap3 + rho * cc0.w * (1.f - cc0.w) - 2.f * tm0.w * cc0.w;
        o.w = fminf(fmaxf(cc0.w + g * delta_t, 0.f), 1.f);
        *reinterpret_cast<float4*>(dst + base0) = o;
    }
    {
        const float lap0 = xl1   + cc1.y + ym1.x + yp1.x + zm1.x + zp1.x - 6.f * cc1.x;
        const float lap1 = cc1.x + cc1.z + ym1.y + yp1.y + zm1.y + zp1.y - 6.f * cc1.y;
        const float lap2 = cc1.y + cc1.w + ym1.z + yp1.z + zm1.z + zp1.z - 6.f * cc1.z;
        const float lap3 = cc1.z + xr1   + ym1.w + yp1.w + zm1.w + zp1.w - 6.f * cc1.w;
        float4 o;
        float g;
        g = D * lap0 + rho * cc1.x * (1.f - cc1.x) - 2.f * tm1.x * cc1.x;
        o.x = fminf(fmaxf(cc1.x + g * delta_t, 0.f), 1.f);
        g = D * lap1 + rho * cc1.y * (1.f - cc1.y) - 2.f * tm1.y * cc1.y;
        o.y = fminf(fmaxf(cc1.y + g * delta_t, 0.f), 1.f);
        g = D * lap2 + rho * cc1.z * (1.f - cc1.z) - 2.f * tm1.z * cc1.z;
        o.z = fminf(fmaxf(cc1.z + g * delta_t, 0.f), 1.f);
        g = D * lap3 + rho * cc1.w * (1.f - cc1.w) - 2.f * tm1.w * cc1.w;
        o.w = fminf(fmaxf(cc1.w + g * delta_t, 0.f), 1.f);
        *reinterpret_cast<float4*>(dst + base1) = o;
    }
}

extern "C" void kernel_launch(void* const* d_in, const int* in_sizes, int n_in,
                              void* d_out, int out_size, void* d_ws, size_t ws_size,
                              hipStream_t stream) {
    const float* c_init = (const float*)d_in[0];
    const float* Dp     = (const float*)d_in[1];
    const float* rhop   = (const float*)d_in[2];
    const float* dtp    = (const float*)d_in[3];
    const float* ther   = (const float*)d_in[4];
    const int*   stepsp = (const int*)d_in[5];

    float* out = (float*)d_out;
    float* wsA = (float*)d_ws;   // ping-pong buffer (16.4 MB)

    // ---- gate the cooperative path (computed once) ----
    static int coop_ok = -1;
    if (coop_ok < 0) {
        coop_ok = 0;
        int dev = 0;
        if (hipGetDevice(&dev) == hipSuccess) {
            int coopAttr = 0, ncu = 0, maxb = 0;
            if (hipDeviceGetAttribute(&coopAttr, hipDeviceAttributeCooperativeLaunch, dev) == hipSuccess &&
                coopAttr != 0 &&
                hipDeviceGetAttribute(&ncu, hipDeviceAttributeMultiprocessorCount, dev) == hipSuccess &&
                hipOccupancyMaxActiveBlocksPerMultiprocessor(
                    &maxb, (const void*)therapy_all, CT_BS, 0) == hipSuccess &&
                (long)maxb * (long)ncu >= (long)CT_NBLOCKS) {
                coop_ok = 1;
            }
        }
    }

    if (coop_ok == 1) {
        void* args[] = {
            (void*)&c_init, (void*)&ther, (void*)&out, (void*)&wsA,
            (void*)&Dp, (void*)&rhop, (void*)&dtp, (void*)&stepsp
        };
        if (hipLaunchCooperativeKernel((void*)therapy_all,
                                       dim3(CT_NBLOCKS), dim3(CT_BS),
                                       args, 0, stream) == hipSuccess) {
            return;
        }
        coop_ok = 0;  // launch rejected -> permanent fallback
    }

    // ---- fallback: 30 per-step launches (proven R2 path) ----
    const dim3 block(256);
    const dim3 grid(FB_NBLOCKS);
    const float* src = c_init;
    for (int i = 0; i < 30; ++i) {
        float* dst = (i & 1) ? out : wsA;
        therapy_step<<<grid, block, 0, stream>>>(src, ther, dst, Dp, rhop, dtp, stepsp);
        src = dst;
    }
}